// Round 3
// baseline (779.562 us; speedup 1.0000x reference)
//
#include <hip/hip_runtime.h>
#include <hip/hip_bf16.h>

// PMA pooling block. Structure:
//  prep:  c,d (scores), constvec, P2b/w1b/w2b bf16 weights, segment starts
//  attn:  one wave per graph, register-resident exp-weighted mean (h read once)
//  epi:   fused o-GEMM -> LN1 -> u-GEMM -> f-GEMM -> LN2 (bf16 MFMA, 1 wave/blk)

#define DIM 256

typedef short bf16x8 __attribute__((ext_vector_type(8)));
typedef float f32x4  __attribute__((ext_vector_type(4)));
#define MFMA16(a, b, c) __builtin_amdgcn_mfma_f32_16x16x32_bf16(a, b, c, 0, 0, 0)

// ---- workspace layout (float offsets) ----
#define OFF_C      0          // c[4][256] fp32
#define OFF_D      1024       // dconst[4]
#define OFF_CONST  1040       // constvec[256]
#define OFF_P2B    2048       // P2 bf16 [256][1024]
#define OFF_W1B    133120     // w1 bf16 [1024][256]
#define OFF_W2B    264192     // w2 bf16 [256][1024]
#define OFF_TB     395264     // T  bf16 [4096][1024]
#define OFF_SEG    2492416    // starts int [G+1]

__device__ inline float dot16(const float4& a0, const float4& a1,
                              const float4& a2, const float4& a3,
                              const float4& b0, const float4& b1,
                              const float4& b2, const float4& b3) {
    return a0.x*b0.x + a0.y*b0.y + a0.z*b0.z + a0.w*b0.w
         + a1.x*b1.x + a1.y*b1.y + a1.z*b1.z + a1.w*b1.w
         + a2.x*b2.x + a2.y*b2.y + a2.z*b2.z + a2.w*b2.w
         + a3.x*b3.x + a3.y*b3.y + a3.z*b3.z + a3.w*b3.w;
}

__device__ inline void fma4(float e, const float4& v, float4& s) {
    s.x = fmaf(e, v.x, s.x); s.y = fmaf(e, v.y, s.y);
    s.z = fmaf(e, v.z, s.z); s.w = fmaf(e, v.w, s.w);
}

// cross-group reduce (xor 16, 32) of a float4
__device__ inline float4 xred(float4 a) {
    a.x += __shfl_xor(a.x, 16); a.y += __shfl_xor(a.y, 16);
    a.z += __shfl_xor(a.z, 16); a.w += __shfl_xor(a.w, 16);
    a.x += __shfl_xor(a.x, 32); a.y += __shfl_xor(a.y, 32);
    a.z += __shfl_xor(a.z, 32); a.w += __shfl_xor(a.w, 32);
    return a;
}

__device__ inline float4 sel4(const float4* S, int q) {
    float4 r = S[0];
    if (q == 1) r = S[1];
    if (q == 2) r = S[2];
    if (q == 3) r = S[3];
    return r;
}

__device__ inline unsigned int pk2(float a, float b) {
    __hip_bfloat16 ha = __float2bfloat16(a), hb = __float2bfloat16(b);
    unsigned short ua, ub;
    __builtin_memcpy(&ua, &ha, 2); __builtin_memcpy(&ub, &hb, 2);
    return (unsigned int)ua | ((unsigned int)ub << 16);
}

// ================= prep: scores consts + bf16 weights + seg starts ======
// blocks 0..1023: P2b; 1024: consts; 1025..1152: w1b; 1153..1280: w2b;
// 1281+: segment starts scan
__global__ __launch_bounds__(256) void prep_all_kernel(
    const float* __restrict__ seed, const float* __restrict__ ipw,
    const float* __restrict__ ipb, const float* __restrict__ out_w,
    const float* __restrict__ out_b, const float* __restrict__ w1,
    const float* __restrict__ w2, const int* __restrict__ batch,
    float* __restrict__ cvec, float* __restrict__ dconst,
    float* __restrict__ constvec, __hip_bfloat16* __restrict__ P2b,
    __hip_bfloat16* __restrict__ w1b, __hip_bfloat16* __restrict__ w2b,
    int* __restrict__ starts, int N, int G)
{
    int b = blockIdx.x, t = threadIdx.x;
    __shared__ float q_s[DIM];
    if (b < 1024) {
        int i = b >> 2, hD = b & 3;
        float a = 0.f;
        for (int j = 0; j < 64; ++j)
            a += out_w[i * DIM + hD * 64 + j]
               * ipw[(size_t)(2 * DIM + hD * 64 + j) * DIM + t];
        P2b[(size_t)i * 1024 + hD * DIM + t] = __float2bfloat16(a);
    } else if (b == 1024) {
        const float scale = 0.125f; // 1/sqrt(64)
        float acc = ipb[t];
        for (int d = 0; d < DIM; ++d) acc += seed[d] * ipw[t * DIM + d];
        q_s[t] = acc;
        __syncthreads();
        for (int hh = 0; hh < 4; ++hh) {
            float a = 0.f;
            for (int j = 0; j < 64; ++j)
                a += q_s[hh * 64 + j] * ipw[(size_t)(DIM + hh * 64 + j) * DIM + t];
            cvec[hh * DIM + t] = a * scale;
        }
        if (t < 4) {
            float a = 0.f;
            for (int j = 0; j < 64; ++j)
                a += q_s[t * 64 + j] * ipb[DIM + t * 64 + j];
            dconst[t] = a * scale;
        }
        float cc = out_b[t];
        for (int c = 0; c < DIM; ++c)
            cc += out_w[t * DIM + c] * ipb[2 * DIM + c];
        constvec[t] = cc;
    } else if (b < 1153) {
        int base = (b - 1025) * 2048 + t;
        for (int i = 0; i < 8; ++i)
            w1b[base + i * 256] = __float2bfloat16(w1[base + i * 256]);
    } else if (b < 1281) {
        int base = (b - 1153) * 2048 + t;
        for (int i = 0; i < 8; ++i)
            w2b[base + i * 256] = __float2bfloat16(w2[base + i * 256]);
    } else {
        int i = (b - 1281) * 256 + t;
        if (i < N) {
            int bi = batch[i];
            if (i == 0) {
                for (int g = 0; g <= bi; ++g) starts[g] = 0;
            } else {
                int bp = batch[i - 1];
                for (int g = bp + 1; g <= bi; ++g) starts[g] = i;
            }
            if (i == N - 1)
                for (int g = bi + 1; g <= G; ++g) starts[g] = N;
        }
    }
}

// ============ attn pooling: 1 wave/graph, register-resident ==============
__global__ __launch_bounds__(64, 2) void attn_pool_kernel(
    const float* __restrict__ hmat, const int* __restrict__ starts,
    const float* __restrict__ cvec, const float* __restrict__ dconst,
    __hip_bfloat16* __restrict__ Tb)
{
    int g = blockIdx.x;
    int lane = threadIdx.x;
    int gq = lane >> 4, l16 = lane & 15;

    int s = starts[g], e = starts[g + 1];

    // c fragments: lane owns dims l16*16..+15 for all 4 heads
    float4 c0[4], c1[4], c2[4], c3[4];
    const float* cb = cvec + l16 * 16;
#pragma unroll
    for (int hh = 0; hh < 4; ++hh) {
        c0[hh] = *(const float4*)(cb + hh * DIM + 0);
        c1[hh] = *(const float4*)(cb + hh * DIM + 4);
        c2[hh] = *(const float4*)(cb + hh * DIM + 8);
        c3[hh] = *(const float4*)(cb + hh * DIM + 12);
    }
    float dc0 = dconst[0], dc1 = dconst[1], dc2 = dconst[2], dc3 = dconst[3];

    float4 S0[4], S1[4], S2[4], S3[4];
#pragma unroll
    for (int hh = 0; hh < 4; ++hh) {
        S0[hh] = make_float4(0, 0, 0, 0); S1[hh] = make_float4(0, 0, 0, 0);
        S2[hh] = make_float4(0, 0, 0, 0); S3[hh] = make_float4(0, 0, 0, 0);
    }
    float l0 = 0.f, l1 = 0.f, l2 = 0.f, l3 = 0.f;

    if (e > s) {
        int nc = min(s + gq, e - 1);
        const float* hp = hmat + (size_t)nc * DIM + l16 * 16;
        float4 v0 = *(const float4*)(hp + 0);
        float4 v1 = *(const float4*)(hp + 4);
        float4 v2 = *(const float4*)(hp + 8);
        float4 v3 = *(const float4*)(hp + 12);
        for (int nb = s; nb < e; nb += 4) {
            bool valid = (nb + gq) < e;
            int nn = min(nb + 4 + gq, e - 1);
            const float* hq = hmat + (size_t)nn * DIM + l16 * 16;
            float4 w0 = *(const float4*)(hq + 0);
            float4 w1v = *(const float4*)(hq + 4);
            float4 w2v = *(const float4*)(hq + 8);
            float4 w3 = *(const float4*)(hq + 12);

            float p0 = dot16(v0, v1, v2, v3, c0[0], c1[0], c2[0], c3[0]);
            float p1 = dot16(v0, v1, v2, v3, c0[1], c1[1], c2[1], c3[1]);
            float p2 = dot16(v0, v1, v2, v3, c0[2], c1[2], c2[2], c3[2]);
            float p3 = dot16(v0, v1, v2, v3, c0[3], c1[3], c2[3], c3[3]);
            // reduce within 16-lane group
            p0 += __shfl_xor(p0, 1); p0 += __shfl_xor(p0, 2);
            p0 += __shfl_xor(p0, 4); p0 += __shfl_xor(p0, 8);
            p1 += __shfl_xor(p1, 1); p1 += __shfl_xor(p1, 2);
            p1 += __shfl_xor(p1, 4); p1 += __shfl_xor(p1, 8);
            p2 += __shfl_xor(p2, 1); p2 += __shfl_xor(p2, 2);
            p2 += __shfl_xor(p2, 4); p2 += __shfl_xor(p2, 8);
            p3 += __shfl_xor(p3, 1); p3 += __shfl_xor(p3, 2);
            p3 += __shfl_xor(p3, 4); p3 += __shfl_xor(p3, 8);

            float e0 = valid ? __expf(p0 + dc0) : 0.f;
            float e1 = valid ? __expf(p1 + dc1) : 0.f;
            float e2 = valid ? __expf(p2 + dc2) : 0.f;
            float e3 = valid ? __expf(p3 + dc3) : 0.f;
            l0 += e0; l1 += e1; l2 += e2; l3 += e3;

            fma4(e0, v0, S0[0]); fma4(e0, v1, S1[0]);
            fma4(e0, v2, S2[0]); fma4(e0, v3, S3[0]);
            fma4(e1, v0, S0[1]); fma4(e1, v1, S1[1]);
            fma4(e1, v2, S2[1]); fma4(e1, v3, S3[1]);
            fma4(e2, v0, S0[2]); fma4(e2, v1, S1[2]);
            fma4(e2, v2, S2[2]); fma4(e2, v3, S3[2]);
            fma4(e3, v0, S0[3]); fma4(e3, v1, S1[3]);
            fma4(e3, v2, S2[3]); fma4(e3, v3, S3[3]);

            v0 = w0; v1 = w1v; v2 = w2v; v3 = w3;
        }
    }

    // cross-group reduction (each group summed a disjoint node subset)
#pragma unroll
    for (int hh = 0; hh < 4; ++hh) {
        S0[hh] = xred(S0[hh]); S1[hh] = xred(S1[hh]);
        S2[hh] = xred(S2[hh]); S3[hh] = xred(S3[hh]);
    }
    l0 += __shfl_xor(l0, 16); l0 += __shfl_xor(l0, 32);
    l1 += __shfl_xor(l1, 16); l1 += __shfl_xor(l1, 32);
    l2 += __shfl_xor(l2, 16); l2 += __shfl_xor(l2, 32);
    l3 += __shfl_xor(l3, 16); l3 += __shfl_xor(l3, 32);

    // group gq writes head gq, dims l16*16..+15
    float lv = gq == 0 ? l0 : gq == 1 ? l1 : gq == 2 ? l2 : l3;
    float iv = (lv > 0.f) ? 1.f / lv : 0.f;
    float4 A0 = sel4(S0, gq), A1 = sel4(S1, gq);
    float4 A2 = sel4(S2, gq), A3 = sel4(S3, gq);
    uint4 o0, o1;
    o0.x = pk2(A0.x * iv, A0.y * iv); o0.y = pk2(A0.z * iv, A0.w * iv);
    o0.z = pk2(A1.x * iv, A1.y * iv); o0.w = pk2(A1.z * iv, A1.w * iv);
    o1.x = pk2(A2.x * iv, A2.y * iv); o1.y = pk2(A2.z * iv, A2.w * iv);
    o1.z = pk2(A3.x * iv, A3.y * iv); o1.w = pk2(A3.z * iv, A3.w * iv);
    uint4* tp = (uint4*)(Tb + (size_t)g * 1024 + gq * 256 + l16 * 16);
    tp[0] = o0; tp[1] = o1;
}

// ======= fused epilogue: o-GEMM -> LN1 -> u-GEMM -> f-GEMM -> LN2 =======
// 1 wave per block, 16 graph rows per block.
__global__ __launch_bounds__(64) void epilogue_kernel(
    const __hip_bfloat16* __restrict__ Tb, const __hip_bfloat16* __restrict__ P2b,
    const __hip_bfloat16* __restrict__ w1b, const __hip_bfloat16* __restrict__ w2b,
    const float* __restrict__ constvec, const float* __restrict__ seed,
    const float* __restrict__ g1, const float* __restrict__ be1,
    const float* __restrict__ b1, const float* __restrict__ b2,
    const float* __restrict__ g2, const float* __restrict__ be2,
    const int* __restrict__ starts, float* __restrict__ outp)
{
    int m0 = blockIdx.x * 16;
    int lane = threadIdx.x, quad = lane >> 4, l16 = lane & 15;
    __shared__ __hip_bfloat16 x1s[16][264];    // pad 8 bf16
    __shared__ __hip_bfloat16 us[16][1048];    // pad 24 bf16

    // ---- Stage A: o = Tb @ P2b^T (K=1024) ----
    f32x4 acc[16];
#pragma unroll
    for (int i = 0; i < 16; ++i) acc[i] = (f32x4){0.f, 0.f, 0.f, 0.f};
    const __hip_bfloat16* Ap = Tb + (size_t)(m0 + l16) * 1024 + quad * 8;
    const __hip_bfloat16* Bp = P2b + (size_t)l16 * 1024 + quad * 8;
    for (int k0 = 0; k0 < 1024; k0 += 32) {
        bf16x8 a = *(const bf16x8*)(Ap + k0);
#pragma unroll
        for (int nt = 0; nt < 16; ++nt) {
            bf16x8 b = *(const bf16x8*)(Bp + (size_t)nt * 16 * 1024 + k0);
            acc[nt] = MFMA16(a, b, acc[nt]);
        }
    }
    // LN1 over o+const+seed -> v (fp32 kept for residual) + x1s (bf16)
    float v[16][4];
    float sum[4] = {0, 0, 0, 0}, sq[4] = {0, 0, 0, 0};
#pragma unroll
    for (int nt = 0; nt < 16; ++nt) {
        int col = nt * 16 + l16;
        float cv = constvec[col] + seed[col];
#pragma unroll
        for (int r = 0; r < 4; ++r) {
            float x = acc[nt][r] + cv;
            v[nt][r] = x; sum[r] += x; sq[r] += x * x;
        }
    }
    float mu_r[4], rs_r[4];
#pragma unroll
    for (int r = 0; r < 4; ++r) {
        float s_ = sum[r], q_ = sq[r];
        s_ += __shfl_xor(s_, 1);  q_ += __shfl_xor(q_, 1);
        s_ += __shfl_xor(s_, 2);  q_ += __shfl_xor(q_, 2);
        s_ += __shfl_xor(s_, 4);  q_ += __shfl_xor(q_, 4);
        s_ += __shfl_xor(s_, 8);  q_ += __shfl_xor(q_, 8);
        float mu = s_ * (1.f / 256);
        float var = q_ * (1.f / 256) - mu * mu;
        mu_r[r] = mu; rs_r[r] = rsqrtf(fmaxf(var, 0.f) + 1e-5f);
    }
#pragma unroll
    for (int nt = 0; nt < 16; ++nt) {
        int col = nt * 16 + l16;
        float gg = g1[col], bb = be1[col];
#pragma unroll
        for (int r = 0; r < 4; ++r) {
            float y = (v[nt][r] - mu_r[r]) * rs_r[r] * gg + bb;
            v[nt][r] = y;
            x1s[quad * 4 + r][col] = __float2bfloat16(y);
        }
    }
    __syncthreads();

    // ---- Stage B: u = relu(x1 @ w1^T + b1), N=1024 in 4 chunks of 256 ----
    for (int c4 = 0; c4 < 4; ++c4) {
        f32x4 ua[16];
#pragma unroll
        for (int i = 0; i < 16; ++i) ua[i] = (f32x4){0.f, 0.f, 0.f, 0.f};
        const __hip_bfloat16* Bp1 = w1b + (size_t)(c4 * 256 + l16) * 256 + quad * 8;
#pragma unroll
        for (int k0 = 0; k0 < 256; k0 += 32) {
            bf16x8 a = *(const bf16x8*)&x1s[l16][k0 + quad * 8];
#pragma unroll
            for (int nt = 0; nt < 16; ++nt) {
                bf16x8 b = *(const bf16x8*)(Bp1 + (size_t)nt * 16 * 256 + k0);
                ua[nt] = MFMA16(a, b, ua[nt]);
            }
        }
#pragma unroll
        for (int nt = 0; nt < 16; ++nt) {
            int col = c4 * 256 + nt * 16 + l16;
            float bb = b1[col];
#pragma unroll
            for (int r = 0; r < 4; ++r)
                us[quad * 4 + r][col] = __float2bfloat16(fmaxf(ua[nt][r] + bb, 0.f));
        }
    }
    __syncthreads();

    // ---- Stage C: f = u @ w2^T (K=1024) ----
    f32x4 fa[16];
#pragma unroll
    for (int i = 0; i < 16; ++i) fa[i] = (f32x4){0.f, 0.f, 0.f, 0.f};
    const __hip_bfloat16* Bp2 = w2b + (size_t)l16 * 1024 + quad * 8;
    for (int k0 = 0; k0 < 1024; k0 += 32) {
        bf16x8 a = *(const bf16x8*)&us[l16][k0 + quad * 8];
#pragma unroll
        for (int nt = 0; nt < 16; ++nt) {
            bf16x8 b = *(const bf16x8*)(Bp2 + (size_t)nt * 16 * 1024 + k0);
            fa[nt] = MFMA16(a, b, fa[nt]);
        }
    }
    // LN2 over x1+f, masked by segment count
    float sum2[4] = {0, 0, 0, 0}, sq2[4] = {0, 0, 0, 0};
#pragma unroll
    for (int nt = 0; nt < 16; ++nt) {
        int col = nt * 16 + l16;
        float bb = b2[col];
#pragma unroll
        for (int r = 0; r < 4; ++r) {
            float x = fa[nt][r] + bb + v[nt][r];
            v[nt][r] = x; sum2[r] += x; sq2[r] += x * x;
        }
    }
#pragma unroll
    for (int r = 0; r < 4; ++r) {
        float s_ = sum2[r], q_ = sq2[r];
        s_ += __shfl_xor(s_, 1);  q_ += __shfl_xor(q_, 1);
        s_ += __shfl_xor(s_, 2);  q_ += __shfl_xor(q_, 2);
        s_ += __shfl_xor(s_, 4);  q_ += __shfl_xor(q_, 4);
        s_ += __shfl_xor(s_, 8);  q_ += __shfl_xor(q_, 8);
        float mu = s_ * (1.f / 256);
        float var = q_ * (1.f / 256) - mu * mu;
        mu_r[r] = mu; rs_r[r] = rsqrtf(fmaxf(var, 0.f) + 1e-5f);
    }
#pragma unroll
    for (int r = 0; r < 4; ++r) {
        int gr = m0 + quad * 4 + r;
        float mask = (starts[gr + 1] > starts[gr]) ? 1.f : 0.f;
#pragma unroll
        for (int nt = 0; nt < 16; ++nt) {
            int col = nt * 16 + l16;
            float y = ((v[nt][r] - mu_r[r]) * rs_r[r] * g2[col] + be2[col]) * mask;
            outp[(size_t)gr * 256 + col] = y;
        }
    }
}

extern "C" void kernel_launch(void* const* d_in, const int* in_sizes, int n_in,
                              void* d_out, int out_size, void* d_ws, size_t ws_size,
                              hipStream_t stream) {
    const float* h     = (const float*)d_in[0];
    const int*   batch = (const int*)d_in[1];
    const float* seed  = (const float*)d_in[3];
    const float* ipw   = (const float*)d_in[4];
    const float* ipb   = (const float*)d_in[5];
    const float* out_w = (const float*)d_in[6];
    const float* out_b = (const float*)d_in[7];
    const float* w1    = (const float*)d_in[8];
    const float* b1    = (const float*)d_in[9];
    const float* w2    = (const float*)d_in[10];
    const float* b2    = (const float*)d_in[11];
    const float* g1    = (const float*)d_in[12];
    const float* be1   = (const float*)d_in[13];
    const float* g2    = (const float*)d_in[14];
    const float* be2   = (const float*)d_in[15];

    int N = in_sizes[1];            // 400000 nodes
    int G = out_size / DIM;         // 4096 graphs

    float* ws = (float*)d_ws;
    float* cvec     = ws + OFF_C;
    float* dconst   = ws + OFF_D;
    float* constvec = ws + OFF_CONST;
    __hip_bfloat16* P2b = (__hip_bfloat16*)(ws + OFF_P2B);
    __hip_bfloat16* w1b = (__hip_bfloat16*)(ws + OFF_W1B);
    __hip_bfloat16* w2b = (__hip_bfloat16*)(ws + OFF_W2B);
    __hip_bfloat16* Tb  = (__hip_bfloat16*)(ws + OFF_TB);
    int* starts     = (int*)(ws + OFF_SEG);

    int seg_blocks = (N + 255) / 256;
    prep_all_kernel<<<1281 + seg_blocks, 256, 0, stream>>>(
        seed, ipw, ipb, out_w, out_b, w1, w2, batch,
        cvec, dconst, constvec, P2b, w1b, w2b, starts, N, G);
    attn_pool_kernel<<<G, 64, 0, stream>>>(h, starts, cvec, dconst, Tb);
    epilogue_kernel<<<G / 16, 64, 0, stream>>>(Tb, P2b, w1b, w2b, constvec, seed,
                                               g1, be1, b1, b2, g2, be2, starts,
                                               (float*)d_out);
}